// Round 14
// baseline (936.263 us; speedup 1.0000x reference)
//
#include <hip/hip_runtime.h>
#include <hip/hip_bf16.h>

#define NN 100000
#define NE 1250000
#define DD 64
#define RR 16
#define NTILE 6250        // NN/16 dst-tiles
#define NBINS 100000      // (dst>>4)*16 + rel
#define NBLK_SCAN 391     // ceil(NBINS/256)
#define EBCAP 512

typedef __attribute__((ext_vector_type(8))) short s16x8;
typedef __attribute__((ext_vector_type(4))) float f32x4;

static __device__ __forceinline__ unsigned short f2bf(float v) {
    __hip_bfloat16 h = __float2bfloat16(v);
    return __builtin_bit_cast(unsigned short, h);
}
static __device__ __forceinline__ unsigned int pack2(float a, float b) {
    return ((unsigned int)f2bf(b) << 16) | (unsigned int)f2bf(a);
}

// ---------------- sort edges by (dst-tile, rel): counting sort, 100k bins ----------------

__global__ void hist_key(const int* __restrict__ dst, const int* __restrict__ et,
                         int* __restrict__ cnt) {
    int e = blockIdx.x * 256 + threadIdx.x;
    if (e < NE) atomicAdd(&cnt[(dst[e] >> 4) * 16 + et[e]], 1);
}

__global__ __launch_bounds__(256) void scan1(const int* __restrict__ cnt,
                                             int* __restrict__ rp, int* __restrict__ part) {
    __shared__ int s[256];
    int i = blockIdx.x * 256 + threadIdx.x;
    int v = (i < NBINS) ? cnt[i] : 0;
    s[threadIdx.x] = v;
    __syncthreads();
    for (int off = 1; off < 256; off <<= 1) {
        int t = (threadIdx.x >= off) ? s[threadIdx.x - off] : 0;
        __syncthreads();
        s[threadIdx.x] += t;
        __syncthreads();
    }
    if (i < NBINS) rp[i] = s[threadIdx.x] - v;        // exclusive
    if (threadIdx.x == 255) part[blockIdx.x] = s[255];
}

__global__ void scan2(int* __restrict__ part, int* __restrict__ rp) {
    __shared__ int s[NBLK_SCAN];
    if (threadIdx.x < NBLK_SCAN) s[threadIdx.x] = part[threadIdx.x];
    __syncthreads();
    if (threadIdx.x == 0) {
        int acc = 0;
        for (int b = 0; b < NBLK_SCAN; ++b) { int t = s[b]; s[b] = acc; acc += t; }
        rp[NBINS] = NE;
    }
    __syncthreads();
    if (threadIdx.x < NBLK_SCAN) part[threadIdx.x] = s[threadIdx.x];
}

__global__ void scan3(int* __restrict__ rp, const int* __restrict__ part, int* __restrict__ cur) {
    int i = blockIdx.x * 256 + threadIdx.x;
    if (i < NBINS) {
        int v = rp[i] + part[blockIdx.x];
        rp[i] = v;
        cur[i] = v;
    }
}

// ep[p] = src | (dst&15)<<20
__global__ void scatter_key(const int* __restrict__ src, const int* __restrict__ dst,
                            const int* __restrict__ et, int* __restrict__ cur,
                            unsigned int* __restrict__ ep) {
    int e = blockIdx.x * 256 + threadIdx.x;
    if (e >= NE) return;
    int d = dst[e];
    int p = atomicAdd(&cur[(d >> 4) * 16 + et[e]], 1);
    ep[p] = (unsigned int)src[e] | ((unsigned int)(d & 15) << 20);
}

// ---------------- precision prep ----------------

__global__ void prep_w2(const float* __restrict__ W1, const float* __restrict__ sw1,
                        const float* __restrict__ W2, const float* __restrict__ sw2,
                        unsigned short* __restrict__ wt) {
    int i = blockIdx.x * 256 + threadIdx.x;
    if (i >= 2 * 17 * DD * DD) return;
    int d = i & 63;
    int o = (i >> 6) & 63;
    int p = (i >> 12) % 17;
    int l = i / (17 * DD * DD);
    const float* srcp;
    if (p < 16) srcp = (l ? W2 : W1) + p * DD * DD;
    else        srcp = (l ? sw2 : sw1);
    wt[i] = f2bf(srcp[d * DD + o]);
}

__global__ void prep_x2(const float* __restrict__ x, unsigned short* __restrict__ xb) {
    int i = blockIdx.x * blockDim.x + threadIdx.x;
    if (i < NN * DD) xb[i] = f2bf(x[i]);
}

// ---------------- fused layer helpers (R10-verified math) ----------------

static __device__ __forceinline__ void load_chunk(
    const unsigned short* __restrict__ xb,
    const unsigned int* __restrict__ esrc, int ebase,
    int b0, int s1, int c, int q,
    s16x8& aA0, s16x8& aA1, s16x8& aB0, s16x8& aB1,
    int& dlA, int& dlB, bool& hasB)
{
    hasB = (s1 - b0) > 16;
    int eA = min(b0 + c, s1 - 1);
    unsigned int wa = esrc[eA - ebase];
    int srcA = (int)(wa & 0xFFFFF);
    dlA = (b0 + c < s1) ? (int)(wa >> 20) : 31;
    const unsigned short* xrA = xb + (size_t)srcA * DD + q * 8;
    aA0 = *(const s16x8*)(xrA);
    aA1 = *(const s16x8*)(xrA + 32);
    dlB = 31;
    if (hasB) {
        int eB = min(b0 + 16 + c, s1 - 1);
        unsigned int wb = esrc[eB - ebase];
        int srcB = (int)(wb & 0xFFFFF);
        dlB = (b0 + 16 + c < s1) ? (int)(wb >> 20) : 31;
        const unsigned short* xrB = xb + (size_t)srcB * DD + q * 8;
        aB0 = *(const s16x8*)(xrB);
        aB1 = *(const s16x8*)(xrB + 32);
    } else {
        aB0 = aA0;
        aB1 = aA1;
    }
}

static __device__ __forceinline__ void compute_chunk4(
    const unsigned short* __restrict__ wt, int r, int c, int q,
    const s16x8& aA0, const s16x8& aA1, const s16x8& aB0, const s16x8& aB1,
    int dlA, int dlB, bool hasB, f32x4* D)
{
    s16x8 a2;
    #pragma unroll
    for (int j = 0; j < 4; ++j) {
        int dj = __shfl(dlA, q * 4 + j, 64);
        a2[j] = (dj == c) ? (short)0x3F80 : (short)0;
    }
    #pragma unroll
    for (int j = 0; j < 4; ++j) {
        int dj = hasB ? __shfl(dlB, q * 4 + j, 64) : 31;
        a2[j + 4] = (dj == c) ? (short)0x3F80 : (short)0;
    }
    #pragma unroll
    for (int ob = 0; ob < 4; ++ob) {
        const unsigned short* wrow = wt + r * (DD * DD) + (ob * 16 + c) * DD + q * 8;
        s16x8 w0 = *(const s16x8*)(wrow);
        s16x8 w1 = *(const s16x8*)(wrow + 32);
        f32x4 cA = {0.f, 0.f, 0.f, 0.f};
        cA = __builtin_amdgcn_mfma_f32_16x16x32_bf16(aA0, w0, cA, 0, 0, 0);
        cA = __builtin_amdgcn_mfma_f32_16x16x32_bf16(aA1, w1, cA, 0, 0, 0);
        s16x8 b2;
        if (hasB) {
            f32x4 cB = {0.f, 0.f, 0.f, 0.f};
            cB = __builtin_amdgcn_mfma_f32_16x16x32_bf16(aB0, w0, cB, 0, 0, 0);
            cB = __builtin_amdgcn_mfma_f32_16x16x32_bf16(aB1, w1, cB, 0, 0, 0);
            #pragma unroll
            for (int j = 0; j < 4; ++j) {
                b2[j]     = (short)f2bf(cA[j]);
                b2[j + 4] = (short)f2bf(cB[j]);
            }
        } else {
            #pragma unroll
            for (int j = 0; j < 4; ++j) {
                b2[j]     = (short)f2bf(cA[j]);
                b2[j + 4] = 0;
            }
        }
        D[ob] = __builtin_amdgcn_mfma_f32_16x16x32_bf16(a2, b2, D[ob], 0, 0, 0);
    }
}

// ---------------- fused layer: 512 threads, 8 waves per tile ----------------
// Wave w owns rels {w, w+8} (+self on wave 0), computes all 64 channels (D[4]);
// partials summed across the 8 wave planes in LDS. Same math as R10 (absmax 0.5).
// __launch_bounds__(512, 8): VGPR<=64 so 4 blocks (32 waves) fit per CU.
__global__ __launch_bounds__(512, 8) void fused_layer(
    const unsigned short* __restrict__ xb,   // [N][64] bf16 layer input
    const unsigned short* __restrict__ wt,   // [17][64][64] bf16 (o-major, d inner)
    const int* __restrict__ rp,              // [NBINS+1]
    const unsigned int* __restrict__ ep,     // [E] src | dstloc<<20
    const float* __restrict__ bias,
    const float* __restrict__ xres,          // fp32 residual or nullptr
    unsigned short* __restrict__ outb,       // bf16 out (layer 1) or nullptr
    float* __restrict__ outf)                // fp32 out (layer 2) or nullptr
{
    __shared__ unsigned int eb[EBCAP];       // 2 KB staged edge words
    __shared__ int rps[17];
    __shared__ float Dred[8 * 1024];         // 32 KB partial-D (8 wave planes)
    const int tid  = threadIdx.x;
    const int wid  = tid >> 6;               // 0..7
    const int lane = tid & 63;
    const int c = lane & 15;
    const int q = lane >> 4;
    const int tile = blockIdx.x;
    const int n0 = tile * 16;

    const int e0 = rp[tile * 16];            // uniform (scalar) loads
    const int cnt = rp[tile * 16 + 16] - e0;
    if (tid < 17) rps[tid] = rp[tile * 16 + tid];
    const bool inLds = (cnt <= EBCAP);
    {
        const int nst = min(cnt, EBCAP);
        for (int i = tid; i < nst; i += 512) eb[i] = ep[e0 + i];
    }
    __syncthreads();

    const unsigned int* esrc = inLds ? eb : (ep + e0);   // indexed by (e - e0)
    f32x4 D[4];
    #pragma unroll
    for (int ob = 0; ob < 4; ++ob) D[ob] = (f32x4){0.f, 0.f, 0.f, 0.f};

    for (int r = wid; r < 16; r += 8) {      // wave w: rels {w, w+8}
        const int s0 = rps[r];
        const int s1 = rps[r + 1];
        for (int b0 = s0; b0 < s1; b0 += 32) {
            s16x8 aA0, aA1, aB0, aB1;
            int dlA, dlB;
            bool hB;
            load_chunk(xb, esrc, e0, b0, s1, c, q, aA0, aA1, aB0, aB1, dlA, dlB, hB);
            compute_chunk4(wt, r, c, q, aA0, aA1, aB0, aB1, dlA, dlB, hB, D);
        }
    }

    // self plane (wave 0 only; rows = x of this tile, identity indicator)
    if (wid == 0) {
        const unsigned short* xr = xb + (size_t)(n0 + c) * DD + q * 8;
        s16x8 a0 = *(const s16x8*)(xr);
        s16x8 a1 = *(const s16x8*)(xr + 32);
        s16x8 a2;
        #pragma unroll
        for (int j = 0; j < 4; ++j) {
            a2[j]     = (q * 4 + j == c) ? (short)0x3F80 : (short)0;
            a2[j + 4] = 0;
        }
        #pragma unroll
        for (int ob = 0; ob < 4; ++ob) {
            const unsigned short* wrow = wt + 16 * (DD * DD) + (ob * 16 + c) * DD + q * 8;
            s16x8 w0 = *(const s16x8*)(wrow);
            s16x8 w1 = *(const s16x8*)(wrow + 32);
            f32x4 cA = {0.f, 0.f, 0.f, 0.f};
            cA = __builtin_amdgcn_mfma_f32_16x16x32_bf16(a0, w0, cA, 0, 0, 0);
            cA = __builtin_amdgcn_mfma_f32_16x16x32_bf16(a1, w1, cA, 0, 0, 0);
            s16x8 b2;
            #pragma unroll
            for (int j = 0; j < 4; ++j) {
                b2[j]     = (short)f2bf(cA[j]);
                b2[j + 4] = 0;
            }
            D[ob] = __builtin_amdgcn_mfma_f32_16x16x32_bf16(a2, b2, D[ob], 0, 0, 0);
        }
    }

    // stage partial D: Dred[wid][node*64 + ch]
    {
        float* dred = Dred + wid * 1024;
        #pragma unroll
        for (int ob = 0; ob < 4; ++ob)
            #pragma unroll
            for (int v = 0; v < 4; ++v)
                dred[(q * 4 + v) * 64 + ob * 16 + c] = D[ob][v];
    }
    __syncthreads();

    // reduce 8 partials + bias (+res) + relu; coalesced stores (512 thr x 2 ch)
    {
        const int j = tid * 2;               // 0..1022
        const int node = j >> 6, ch = j & 63;
        float v0 = 0.f, v1 = 0.f;
        #pragma unroll
        for (int p = 0; p < 8; ++p) {
            v0 += Dred[p * 1024 + j];
            v1 += Dred[p * 1024 + j + 1];
        }
        v0 += bias[ch];
        v1 += bias[ch + 1];
        if (xres) {
            const float2 rv = *(const float2*)(xres + (size_t)(n0 + node) * DD + ch);
            v0 += rv.x; v1 += rv.y;
        }
        v0 = fmaxf(v0, 0.f);
        v1 = fmaxf(v1, 0.f);
        if (outb)
            *(unsigned int*)(outb + (size_t)(n0 + node) * DD + ch) = pack2(v0, v1);
        if (outf) {
            float2 o = {v0, v1};
            *(float2*)(outf + (size_t)(n0 + node) * DD + ch) = o;
        }
    }
}

// ================= launch =================

extern "C" void kernel_launch(void* const* d_in, const int* in_sizes, int n_in,
                              void* d_out, int out_size, void* d_ws, size_t ws_size,
                              hipStream_t stream)
{
    (void)in_sizes; (void)n_in; (void)out_size; (void)ws_size;
    const float* x    = (const float*)d_in[0];
    const int*   ei   = (const int*)d_in[1];
    const int*   et   = (const int*)d_in[2];
    const float* W1   = (const float*)d_in[3];
    const float* sw1  = (const float*)d_in[4];
    const float* b1   = (const float*)d_in[5];
    const float* W2   = (const float*)d_in[6];
    const float* sw2  = (const float*)d_in[7];
    const float* b2   = (const float*)d_in[8];
    float* out = (float*)d_out;

    const int* srcA = ei;
    const int* dstA = ei + NE;

    char* ws = (char*)d_ws;
    unsigned short* xb   = (unsigned short*)(ws);                 // 12,800,000
    unsigned short* h1b  = (unsigned short*)(ws + 12800000);      // 12,800,000
    unsigned short* wt2  = (unsigned short*)(ws + 25600000);      //    278,528
    unsigned int*   ep   = (unsigned int*)(ws + 25878528);        //  5,000,000
    int*            rp   = (int*)(ws + 30878528);                 //    400,004
    int*            cnt  = (int*)(ws + 31278544);                 //    400,000
    int*            cur  = (int*)(ws + 31678544);                 //    400,000
    int*            part = (int*)(ws + 32078544);                 //      1,600

    const int NB_E    = (NE + 255) / 256;        // 4883
    const int NB_ELEM = (NN * DD + 255) / 256;   // 25000
    const int WPL = 17 * DD * DD;                // wt2 per-layer stride

    // sort edges by (dst-tile, rel) — once, reused by both layers
    hipMemsetAsync(cnt, 0, NBINS * sizeof(int), stream);
    hist_key<<<NB_E, 256, 0, stream>>>(dstA, et, cnt);
    scan1<<<NBLK_SCAN, 256, 0, stream>>>(cnt, rp, part);
    scan2<<<1, 512, 0, stream>>>(part, rp);
    scan3<<<NBLK_SCAN, 256, 0, stream>>>(rp, part, cur);
    scatter_key<<<NB_E, 256, 0, stream>>>(srcA, dstA, et, cur, ep);

    // precision prep
    prep_w2<<<(2 * 17 * DD * DD + 255) / 256, 256, 0, stream>>>(W1, sw1, W2, sw2, wt2);
    prep_x2<<<NB_ELEM, 256, 0, stream>>>(x, xb);

    // ---- layer 1 (residual) ----
    fused_layer<<<NTILE, 512, 0, stream>>>(xb, wt2, rp, ep, b1, x, h1b, nullptr);
    // ---- layer 2 (no residual) ----
    fused_layer<<<NTILE, 512, 0, stream>>>(h1b, wt2 + WPL, rp, ep, b2, nullptr, nullptr, out);
}

// Round 15
// 542.854 us; speedup vs baseline: 1.7247x; 1.7247x over previous
//
#include <hip/hip_runtime.h>
#include <hip/hip_bf16.h>

#define NN 100000
#define NE 1250000
#define DD 64
#define RR 16
#define NTILE 6250        // NN/16 dst-tiles
#define NBINS 100000      // (dst>>4)*16 + rel
#define NBLK_SCAN 391     // ceil(NBINS/256)

typedef __attribute__((ext_vector_type(8))) short s16x8;
typedef __attribute__((ext_vector_type(4))) float f32x4;

static __device__ __forceinline__ unsigned short f2bf(float v) {
    __hip_bfloat16 h = __float2bfloat16(v);
    return __builtin_bit_cast(unsigned short, h);
}
static __device__ __forceinline__ unsigned int pack2(float a, float b) {
    return ((unsigned int)f2bf(b) << 16) | (unsigned int)f2bf(a);
}

// ---------------- sort edges by (dst-tile, rel): counting sort, 100k bins ----------------

__global__ void hist_key(const int* __restrict__ dst, const int* __restrict__ et,
                         int* __restrict__ cnt) {
    int e = blockIdx.x * 256 + threadIdx.x;
    if (e < NE) atomicAdd(&cnt[(dst[e] >> 4) * 16 + et[e]], 1);
}

__global__ __launch_bounds__(256) void scan1(const int* __restrict__ cnt,
                                             int* __restrict__ rp, int* __restrict__ part) {
    __shared__ int s[256];
    int i = blockIdx.x * 256 + threadIdx.x;
    int v = (i < NBINS) ? cnt[i] : 0;
    s[threadIdx.x] = v;
    __syncthreads();
    for (int off = 1; off < 256; off <<= 1) {
        int t = (threadIdx.x >= off) ? s[threadIdx.x - off] : 0;
        __syncthreads();
        s[threadIdx.x] += t;
        __syncthreads();
    }
    if (i < NBINS) rp[i] = s[threadIdx.x] - v;        // exclusive
    if (threadIdx.x == 255) part[blockIdx.x] = s[255];
}

__global__ void scan2(int* __restrict__ part, int* __restrict__ rp) {
    __shared__ int s[NBLK_SCAN];
    if (threadIdx.x < NBLK_SCAN) s[threadIdx.x] = part[threadIdx.x];
    __syncthreads();
    if (threadIdx.x == 0) {
        int acc = 0;
        for (int b = 0; b < NBLK_SCAN; ++b) { int t = s[b]; s[b] = acc; acc += t; }
        rp[NBINS] = NE;
    }
    __syncthreads();
    if (threadIdx.x < NBLK_SCAN) part[threadIdx.x] = s[threadIdx.x];
}

__global__ void scan3(int* __restrict__ rp, const int* __restrict__ part, int* __restrict__ cur) {
    int i = blockIdx.x * 256 + threadIdx.x;
    if (i < NBINS) {
        int v = rp[i] + part[blockIdx.x];
        rp[i] = v;
        cur[i] = v;
    }
}

// ep[p] = src | (dst&15)<<20
__global__ void scatter_key(const int* __restrict__ src, const int* __restrict__ dst,
                            const int* __restrict__ et, int* __restrict__ cur,
                            unsigned int* __restrict__ ep) {
    int e = blockIdx.x * 256 + threadIdx.x;
    if (e >= NE) return;
    int d = dst[e];
    int p = atomicAdd(&cur[(d >> 4) * 16 + et[e]], 1);
    ep[p] = (unsigned int)src[e] | ((unsigned int)(d & 15) << 20);
}

// ---------------- precision prep ----------------

__global__ void prep_w2(const float* __restrict__ W1, const float* __restrict__ sw1,
                        const float* __restrict__ W2, const float* __restrict__ sw2,
                        unsigned short* __restrict__ wt) {
    int i = blockIdx.x * 256 + threadIdx.x;
    if (i >= 2 * 17 * DD * DD) return;
    int d = i & 63;
    int o = (i >> 6) & 63;
    int p = (i >> 12) % 17;
    int l = i / (17 * DD * DD);
    const float* srcp;
    if (p < 16) srcp = (l ? W2 : W1) + p * DD * DD;
    else        srcp = (l ? sw2 : sw1);
    wt[i] = f2bf(srcp[d * DD + o]);
}

__global__ void prep_x2(const float* __restrict__ x, unsigned short* __restrict__ xb) {
    int i = blockIdx.x * blockDim.x + threadIdx.x;
    if (i < NN * DD) xb[i] = f2bf(x[i]);
}

// ---------------- fused layer: R10 math, direct-ep, shuffle-free, 1 barrier ----------------
// Block = 16-dst tile, wave w owns rels {w, w+4, w+8, w+12} (+self on wave 0);
// each wave computes all 64 channels (D[4]); 4 partials summed in LDS.
// Indicator words are loaded directly from ep (hot line) instead of shuffled,
// so per-chunk loads (indicator x2, src word, x-gathers x4) are all independent.
__global__ __launch_bounds__(256) void fused_layer(
    const unsigned short* __restrict__ xb,   // [N][64] bf16 layer input
    const unsigned short* __restrict__ wt,   // [17][64][64] bf16 (o-major, d inner)
    const int* __restrict__ rp,              // [NBINS+1]
    const unsigned int* __restrict__ ep,     // [E] src | dstloc<<20
    const float* __restrict__ bias,
    const float* __restrict__ xres,          // fp32 residual or nullptr
    unsigned short* __restrict__ outb,       // bf16 out (layer 1) or nullptr
    float* __restrict__ outf)                // fp32 out (layer 2) or nullptr
{
    __shared__ float Dred[4 * 1024];         // 16 KB partial-D
    const int tid  = threadIdx.x;
    const int wid  = tid >> 6;
    const int lane = tid & 63;
    const int c = lane & 15;
    const int q = lane >> 4;
    const int tile = blockIdx.x;
    const int n0 = tile * 16;

    f32x4 D[4];
    #pragma unroll
    for (int ob = 0; ob < 4; ++ob) D[ob] = (f32x4){0.f, 0.f, 0.f, 0.f};

    for (int r = wid; r < 16; r += 4) {
        const int s0 = rp[tile * 16 + r];        // uniform -> scalar loads
        const int s1 = rp[tile * 16 + r + 1];

        for (int b0 = s0; b0 < s1; b0 += 32) {
            const bool hasB = (s1 - b0) > 16;

            // src word for this lane's A-row (chunk A: edge b0+c)
            unsigned int wa = ep[min(b0 + c, s1 - 1)];
            int srcA = (int)(wa & 0xFFFFF);
            // indicator words for slots q*4+j (chunk A), loaded directly
            int ia[4], ib[4];
            #pragma unroll
            for (int j = 0; j < 4; ++j)
                ia[j] = (b0 + q * 4 + j < s1) ? (int)(ep[b0 + q * 4 + j] >> 20) : 31;
            int srcB = srcA;
            if (hasB) {
                unsigned int wb = ep[min(b0 + 16 + c, s1 - 1)];
                srcB = (int)(wb & 0xFFFFF);
                #pragma unroll
                for (int j = 0; j < 4; ++j)
                    ib[j] = (b0 + 16 + q * 4 + j < s1) ? (int)(ep[b0 + 16 + q * 4 + j] >> 20) : 31;
            }

            // x gathers (independent of indicator path)
            const unsigned short* xrA = xb + (size_t)srcA * DD + q * 8;
            s16x8 aA0 = *(const s16x8*)(xrA);
            s16x8 aA1 = *(const s16x8*)(xrA + 32);
            s16x8 aB0 = aA0, aB1 = aA1;
            if (hasB) {
                const unsigned short* xrB = xb + (size_t)srcB * DD + q * 8;
                aB0 = *(const s16x8*)(xrB);
                aB1 = *(const s16x8*)(xrB + 32);
            }

            // indicator A2
            s16x8 a2;
            #pragma unroll
            for (int j = 0; j < 4; ++j)
                a2[j] = (ia[j] == c) ? (short)0x3F80 : (short)0;
            #pragma unroll
            for (int j = 0; j < 4; ++j)
                a2[j + 4] = (hasB && ib[j] == c) ? (short)0x3F80 : (short)0;

            #pragma unroll
            for (int ob = 0; ob < 4; ++ob) {
                const unsigned short* wrow = wt + r * (DD * DD) + (ob * 16 + c) * DD + q * 8;
                s16x8 w0 = *(const s16x8*)(wrow);
                s16x8 w1 = *(const s16x8*)(wrow + 32);
                f32x4 cA = {0.f, 0.f, 0.f, 0.f};
                cA = __builtin_amdgcn_mfma_f32_16x16x32_bf16(aA0, w0, cA, 0, 0, 0);
                cA = __builtin_amdgcn_mfma_f32_16x16x32_bf16(aA1, w1, cA, 0, 0, 0);
                s16x8 b2;
                if (hasB) {
                    f32x4 cB = {0.f, 0.f, 0.f, 0.f};
                    cB = __builtin_amdgcn_mfma_f32_16x16x32_bf16(aB0, w0, cB, 0, 0, 0);
                    cB = __builtin_amdgcn_mfma_f32_16x16x32_bf16(aB1, w1, cB, 0, 0, 0);
                    #pragma unroll
                    for (int j = 0; j < 4; ++j) {
                        b2[j]     = (short)f2bf(cA[j]);
                        b2[j + 4] = (short)f2bf(cB[j]);
                    }
                } else {
                    #pragma unroll
                    for (int j = 0; j < 4; ++j) {
                        b2[j]     = (short)f2bf(cA[j]);
                        b2[j + 4] = 0;
                    }
                }
                D[ob] = __builtin_amdgcn_mfma_f32_16x16x32_bf16(a2, b2, D[ob], 0, 0, 0);
            }
        }
    }

    // self plane (wave 0 only; rows = x of this tile, identity indicator)
    if (wid == 0) {
        const unsigned short* xr = xb + (size_t)(n0 + c) * DD + q * 8;
        s16x8 a0 = *(const s16x8*)(xr);
        s16x8 a1 = *(const s16x8*)(xr + 32);
        s16x8 a2;
        #pragma unroll
        for (int j = 0; j < 4; ++j) {
            a2[j]     = (q * 4 + j == c) ? (short)0x3F80 : (short)0;
            a2[j + 4] = 0;
        }
        #pragma unroll
        for (int ob = 0; ob < 4; ++ob) {
            const unsigned short* wrow = wt + 16 * (DD * DD) + (ob * 16 + c) * DD + q * 8;
            s16x8 w0 = *(const s16x8*)(wrow);
            s16x8 w1 = *(const s16x8*)(wrow + 32);
            f32x4 cA = {0.f, 0.f, 0.f, 0.f};
            cA = __builtin_amdgcn_mfma_f32_16x16x32_bf16(a0, w0, cA, 0, 0, 0);
            cA = __builtin_amdgcn_mfma_f32_16x16x32_bf16(a1, w1, cA, 0, 0, 0);
            s16x8 b2;
            #pragma unroll
            for (int j = 0; j < 4; ++j) {
                b2[j]     = (short)f2bf(cA[j]);
                b2[j + 4] = 0;
            }
            D[ob] = __builtin_amdgcn_mfma_f32_16x16x32_bf16(a2, b2, D[ob], 0, 0, 0);
        }
    }

    // stage partial D: Dred[wid][node*64 + ch]
    {
        float* dred = Dred + wid * 1024;
        #pragma unroll
        for (int ob = 0; ob < 4; ++ob)
            #pragma unroll
            for (int v = 0; v < 4; ++v)
                dred[(q * 4 + v) * 64 + ob * 16 + c] = D[ob][v];
    }
    __syncthreads();

    // reduce 4 partials + bias (+res) + relu; coalesced stores
    #pragma unroll
    for (int k = 0; k < 2; ++k) {
        int j = k * 512 + tid * 2;
        int node = j >> 6, ch = j & 63;
        float v0 = Dred[j]        + Dred[1024 + j]     + Dred[2048 + j]     + Dred[3072 + j];
        float v1 = Dred[j + 1]    + Dred[1024 + j + 1] + Dred[2048 + j + 1] + Dred[3072 + j + 1];
        v0 += bias[ch];
        v1 += bias[ch + 1];
        if (xres) {
            const float2 rv = *(const float2*)(xres + (size_t)(n0 + node) * DD + ch);
            v0 += rv.x; v1 += rv.y;
        }
        v0 = fmaxf(v0, 0.f);
        v1 = fmaxf(v1, 0.f);
        if (outb)
            *(unsigned int*)(outb + (size_t)(n0 + node) * DD + ch) = pack2(v0, v1);
        if (outf) {
            float2 o = {v0, v1};
            *(float2*)(outf + (size_t)(n0 + node) * DD + ch) = o;
        }
    }
}

// ================= launch =================

extern "C" void kernel_launch(void* const* d_in, const int* in_sizes, int n_in,
                              void* d_out, int out_size, void* d_ws, size_t ws_size,
                              hipStream_t stream)
{
    (void)in_sizes; (void)n_in; (void)out_size; (void)ws_size;
    const float* x    = (const float*)d_in[0];
    const int*   ei   = (const int*)d_in[1];
    const int*   et   = (const int*)d_in[2];
    const float* W1   = (const float*)d_in[3];
    const float* sw1  = (const float*)d_in[4];
    const float* b1   = (const float*)d_in[5];
    const float* W2   = (const float*)d_in[6];
    const float* sw2  = (const float*)d_in[7];
    const float* b2   = (const float*)d_in[8];
    float* out = (float*)d_out;

    const int* srcA = ei;
    const int* dstA = ei + NE;

    char* ws = (char*)d_ws;
    unsigned short* xb   = (unsigned short*)(ws);                 // 12,800,000
    unsigned short* h1b  = (unsigned short*)(ws + 12800000);      // 12,800,000
    unsigned short* wt2  = (unsigned short*)(ws + 25600000);      //    278,528
    unsigned int*   ep   = (unsigned int*)(ws + 25878528);        //  5,000,000
    int*            rp   = (int*)(ws + 30878528);                 //    400,004
    int*            cnt  = (int*)(ws + 31278544);                 //    400,000
    int*            cur  = (int*)(ws + 31678544);                 //    400,000
    int*            part = (int*)(ws + 32078544);                 //      1,600

    const int NB_E    = (NE + 255) / 256;        // 4883
    const int NB_ELEM = (NN * DD + 255) / 256;   // 25000
    const int WPL = 17 * DD * DD;                // wt2 per-layer stride

    // sort edges by (dst-tile, rel) — once, reused by both layers
    hipMemsetAsync(cnt, 0, NBINS * sizeof(int), stream);
    hist_key<<<NB_E, 256, 0, stream>>>(dstA, et, cnt);
    scan1<<<NBLK_SCAN, 256, 0, stream>>>(cnt, rp, part);
    scan2<<<1, 512, 0, stream>>>(part, rp);
    scan3<<<NBLK_SCAN, 256, 0, stream>>>(rp, part, cur);
    scatter_key<<<NB_E, 256, 0, stream>>>(srcA, dstA, et, cur, ep);

    // precision prep
    prep_w2<<<(2 * 17 * DD * DD + 255) / 256, 256, 0, stream>>>(W1, sw1, W2, sw2, wt2);
    prep_x2<<<NB_ELEM, 256, 0, stream>>>(x, xb);

    // ---- layer 1 (residual) ----
    fused_layer<<<NTILE, 256, 0, stream>>>(xb, wt2, rp, ep, b1, x, h1b, nullptr);
    // ---- layer 2 (no residual) ----
    fused_layer<<<NTILE, 256, 0, stream>>>(h1b, wt2 + WPL, rp, ep, b2, nullptr, nullptr, out);
}